// Round 1
// baseline (339.026 us; speedup 1.0000x reference)
//
#include <hip/hip_runtime.h>
#include <float.h>

#define BLK 256

__global__ __launch_bounds__(BLK) void chamfer_kernel(
    const float* __restrict__ xyz1,
    const float* __restrict__ xyz2,
    float* __restrict__ out,
    int B, int N, int M)
{
    const int dir = blockIdx.z;   // 0: query=xyz1 target=xyz2 ; 1: reversed
    const int b   = blockIdx.y;
    const float* __restrict__ Q = (dir == 0) ? xyz1 : xyz2;
    const float* __restrict__ T = (dir == 0) ? xyz2 : xyz1;
    const int nQ = (dir == 0) ? N : M;
    const int nT = (dir == 0) ? M : N;

    const int i = blockIdx.x * BLK + threadIdx.x;

    // Query point held in registers (out-of-range lanes compute garbage, never store).
    float x0 = 0.f, x1 = 0.f, x2 = 0.f;
    if (i < nQ) {
        const float* q = Q + ((size_t)b * nQ + i) * 3;
        x0 = q[0]; x1 = q[1]; x2 = q[2];
    }

    // Target points: block-uniform loop -> these float4 loads should become
    // s_load_dwordx4 (SMEM pipe), costing zero VALU/LDS bandwidth.
    // Base is 16B-aligned: b*nT*3*4 bytes = b*98304, xyz base is page-aligned.
    const float4* __restrict__ T4 =
        reinterpret_cast<const float4*>(T + (size_t)b * nT * 3);

    auto dist = [&](float y0, float y1, float y2) -> float {
        float t0 = y0 - x0, t1 = y1 - x1, t2 = y2 - x2;
        return fmaf(t0, t0, fmaf(t1, t1, t2 * t2));
    };

    // 4 independent partial mins break the v_min_f32 dependency chain.
    float b0 = FLT_MAX, b1 = FLT_MAX, b2 = FLT_MAX, b3 = FLT_MAX;

    int j = 0;
    for (; j + 8 <= nT; j += 8) {
        const int base = (j >> 2) * 3;   // float4 index; 8 points = 6 float4s
        const float4 a0 = T4[base + 0];
        const float4 a1 = T4[base + 1];
        const float4 a2 = T4[base + 2];
        const float4 a3 = T4[base + 3];
        const float4 a4 = T4[base + 4];
        const float4 a5 = T4[base + 5];
        b0 = fminf(b0, dist(a0.x, a0.y, a0.z));
        b1 = fminf(b1, dist(a0.w, a1.x, a1.y));
        b2 = fminf(b2, dist(a1.z, a1.w, a2.x));
        b3 = fminf(b3, dist(a2.y, a2.z, a2.w));
        b0 = fminf(b0, dist(a3.x, a3.y, a3.z));
        b1 = fminf(b1, dist(a3.w, a4.x, a4.y));
        b2 = fminf(b2, dist(a4.z, a4.w, a5.x));
        b3 = fminf(b3, dist(a5.y, a5.z, a5.w));
    }
    for (; j < nT; ++j) {   // generic tail (not hit for 8192, kept for safety)
        const float* t = T + ((size_t)b * nT + j) * 3;
        b0 = fminf(b0, dist(t[0], t[1], t[2]));
    }

    if (i < nQ) {
        const size_t off = (dir == 0) ? ((size_t)b * N + i)
                                      : ((size_t)B * N + (size_t)b * M + i);
        out[off] = fminf(fminf(b0, b1), fminf(b2, b3));
    }
}

extern "C" void kernel_launch(void* const* d_in, const int* in_sizes, int n_in,
                              void* d_out, int out_size, void* d_ws, size_t ws_size,
                              hipStream_t stream) {
    const float* xyz1 = (const float*)d_in[0];
    const float* xyz2 = (const float*)d_in[1];
    float* out = (float*)d_out;

    // Shapes per reference: xyz1 [B,N,3], xyz2 [B,M,3]
    const int B = 8, N = 8192, M = 8192;

    const int nmax = (N > M) ? N : M;
    dim3 grid((unsigned)((nmax + BLK - 1) / BLK), (unsigned)B, 2);
    chamfer_kernel<<<grid, dim3(BLK, 1, 1), 0, stream>>>(xyz1, xyz2, out, B, N, M);
}